// Round 1
// baseline (112.618 us; speedup 1.0000x reference)
//
#include <hip/hip_runtime.h>
#include <math.h>

#define BB 8
#define CC 64
#define HH 32
#define WW 32
#define HW 1024
#define NEGN 256
#define TEMP 2.0f
#define FACTOR 0.8f
#define EPSF 1e-8f
#define PT 8            // p-rows per block

// ---------------------------------------------------------------------------
// Fused kernel: one block per (b, p-tile of 8 rows).
// Phase A: dense GEMM D[pp][q] = sum_c z1[b,c,p0+pp] * z2[b,c,q] for all q,
//          coalesced float4 streaming of z2[b] (L2-resident), accumulators in
//          registers, result + per-q norms written to LDS.
// Phase B: n = threadIdx.x mapping. Per-thread loop over the 8 pp's:
//          weight terms reduced by a full-wave butterfly + 256B cross-wave
//          buffer; per-n sum over pp accumulates IN REGISTERS -> one global
//          atomic per thread. img is NOT staged (12KB, L1-resident; random
//          gathers hit L1 and overlap other resident blocks' Phase A).
// LDS: 2 + 32 + 4 + ~0.4 = 38.4 KB  -> 4 workgroups resident per CU
//      (vs 58 KB -> 2 WGs before). All 4 blocks/CU co-resident in one round.
// ---------------------------------------------------------------------------
__global__ __launch_bounds__(256, 4) void contrastive_fused(
    const float* __restrict__ z1,    // (B, C, HW)
    const float* __restrict__ z2,    // (B, C, HW)
    const float* __restrict__ img,   // (3, HW)
    const int*   __restrict__ nidx,  // (B, 2, HW, NEG)
    float* __restrict__ accSim,      // (B, NEG)
    float* __restrict__ accSim0)     // (B)
{
    __shared__ float As_s[CC * PT];       // [c][pp]   2 KB
    __shared__ float Dt_s[PT * HW];       // [pp][q]  32 KB
    __shared__ float normq_s[HW];         //           4 KB
    __shared__ float cen_s[3 * PT];       // [ch][pp]  96 B
    __shared__ float z1sqs[PT];           //           32 B
    __shared__ float wred_s[PT][4][2];    // [pp][wave][se|sr] 256 B

    const int t  = threadIdx.x;           // == n in phase B
    const int b  = blockIdx.x >> 7;
    const int p0 = (blockIdx.x & 127) * PT;

    // ---- stage z1 panel + per-pp img centers into LDS ----
    for (int i = t; i < CC * PT; i += 256) {
        const int c = i >> 3, pp = i & 7;
        As_s[i] = z1[((size_t)(b * CC + c)) * HW + p0 + pp];
    }
    if (t < 3 * PT) cen_s[t] = img[(t >> 3) * HW + p0 + (t & 7)];
    __syncthreads();

    if (t < PT) {
        float s = 0.f;
        #pragma unroll
        for (int c = 0; c < CC; ++c) { const float v = As_s[c * PT + t]; s += v * v; }
        z1sqs[t] = s;
    }

    // ---- phase A: GEMM, thread t owns q = 4t..4t+3 for all 8 p ----
    const float4* __restrict__ z2f4 =
        reinterpret_cast<const float4*>(z2 + (size_t)b * CC * HW);
    float4 acc[PT];
    #pragma unroll
    for (int pp = 0; pp < PT; ++pp) acc[pp] = make_float4(0.f, 0.f, 0.f, 0.f);
    float4 sq = make_float4(0.f, 0.f, 0.f, 0.f);

    #pragma unroll 8
    for (int k = 0; k < CC; ++k) {
        const float4 bv = z2f4[k * (HW / 4) + t];
        sq.x = fmaf(bv.x, bv.x, sq.x);
        sq.y = fmaf(bv.y, bv.y, sq.y);
        sq.z = fmaf(bv.z, bv.z, sq.z);
        sq.w = fmaf(bv.w, bv.w, sq.w);
        const float4 a03 = reinterpret_cast<const float4*>(As_s)[k * 2];
        const float4 a47 = reinterpret_cast<const float4*>(As_s)[k * 2 + 1];
        const float av[8] = {a03.x, a03.y, a03.z, a03.w, a47.x, a47.y, a47.z, a47.w};
        #pragma unroll
        for (int pp = 0; pp < PT; ++pp) {
            acc[pp].x = fmaf(av[pp], bv.x, acc[pp].x);
            acc[pp].y = fmaf(av[pp], bv.y, acc[pp].y);
            acc[pp].z = fmaf(av[pp], bv.z, acc[pp].z);
            acc[pp].w = fmaf(av[pp], bv.w, acc[pp].w);
        }
    }
    float4* Dt4 = reinterpret_cast<float4*>(Dt_s);
    #pragma unroll
    for (int pp = 0; pp < PT; ++pp) Dt4[pp * (HW / 4) + t] = acc[pp];
    reinterpret_cast<float4*>(normq_s)[t] =
        make_float4(sqrtf(sq.x), sqrtf(sq.y), sqrtf(sq.z), sqrtf(sq.w));

    // ---- prefetch nidx for this thread's n (=t), issued before the barrier
    //      so the HBM latency hides under the barrier drain ----
    int rr[PT], cc_[PT];
    const size_t nb0 = ((size_t)(b * 2) * HW + p0) * NEGN;
    #pragma unroll
    for (int pp = 0; pp < PT; ++pp) {
        rr[pp]  = nidx[nb0 + (size_t)pp * NEGN + t];
        cc_[pp] = nidx[nb0 + (size_t)HW * NEGN + (size_t)pp * NEGN + t];
    }
    __syncthreads();

    // ---- phase B pass 1: per-pp weight partials for this n ----
    float se[PT], sr[PT];
    #pragma unroll
    for (int pp = 0; pp < PT; ++pp) {
        const int q  = rr[pp] * WW + cc_[pp];
        const float hp = (float)((p0 + pp) >> 5);
        const float wp = (float)((p0 + pp) & 31);
        const float dh = hp - (float)rr[pp], dw = wp - (float)cc_[pp];
        se[pp] = dh * dh + dw * dw;
        const float d0 = cen_s[pp]          - img[q];
        const float d1 = cen_s[PT + pp]     - img[HW + q];
        const float d2 = cen_s[2 * PT + pp] - img[2 * HW + q];
        sr[pp] = d0 * d0 + d1 * d1 + d2 * d2;
    }
    // full-wave butterfly: each wave sums its 64 n's for every pp
    #pragma unroll
    for (int off = 32; off; off >>= 1) {
        #pragma unroll
        for (int pp = 0; pp < PT; ++pp) {
            se[pp] += __shfl_xor(se[pp], off);
            sr[pp] += __shfl_xor(sr[pp], off);
        }
    }
    if ((t & 63) == 0) {
        const int wv = t >> 6;
        #pragma unroll
        for (int pp = 0; pp < PT; ++pp) {
            wred_s[pp][wv][0] = se[pp];
            wred_s[pp][wv][1] = sr[pp];
        }
    }
    __syncthreads();

    // ---- phase B pass 2: weight, cos, per-n in-register sum over pp ----
    const float euc_norm = sqrtf((float)((HH - 1) * (HH - 1) + (WW - 1) * (WW - 1)));
    const float wE = FACTOR / euc_norm;
    const float wR = (1.0f - FACTOR) / sqrtf(3.0f);
    float s = 0.f;
    #pragma unroll
    for (int pp = 0; pp < PT; ++pp) {
        const float SE = wred_s[pp][0][0] + wred_s[pp][1][0] +
                         wred_s[pp][2][0] + wred_s[pp][3][0];
        const float SR = wred_s[pp][0][1] + wred_s[pp][1][1] +
                         wred_s[pp][2][1] + wred_s[pp][3][1];
        const float weight = sqrtf(SE) * wE + sqrtf(SR) * wR;
        const int q = rr[pp] * WW + cc_[pp];
        const float dot = Dt_s[pp * HW + q];
        const float cosv = dot / fmaxf(sqrtf(z1sqs[pp]) * normq_s[q], EPSF);
        s += fminf(fabsf(cosv * weight), 1.0f);
    }
    atomicAdd(accSim + b * NEGN + t, s);

    // sim0 contributions (8 p's) -> one atomic per block
    if (t == 0) {
        float s0 = 0.f;
        #pragma unroll
        for (int pp = 0; pp < PT; ++pp) {
            const float c0 = z1sqs[pp] / fmaxf(z1sqs[pp], EPSF);
            s0 += fminf(fabsf(c0), 1.0f);
        }
        atomicAdd(accSim0 + b, s0);
    }
}

// ---------------------------------------------------------------------------
// Finalize: loss is linear in the per-(b,n) sums; one block suffices.
// ---------------------------------------------------------------------------
__global__ __launch_bounds__(256) void finalize(
    const float* __restrict__ accSim,
    const float* __restrict__ accSim0,
    float* __restrict__ out)
{
    const int t = threadIdx.x;
    float ssum = 0.f, lsum = 0.f;
    #pragma unroll
    for (int b = 0; b < BB; ++b) {
        const float s = accSim[b * NEGN + t] * (1.0f / HW) * (1.0f / TEMP);
        ssum += s;
        lsum += fmaxf(log1pf(-s), -100.0f);
    }
    __shared__ float rs[4], rl[4];
    #pragma unroll
    for (int off = 32; off; off >>= 1) {
        ssum += __shfl_down(ssum, off);
        lsum += __shfl_down(lsum, off);
    }
    if ((t & 63) == 0) { rs[t >> 6] = ssum; rl[t >> 6] = lsum; }
    __syncthreads();

    if (t == 0) {
        const float S = rs[0] + rs[1] + rs[2] + rs[3];
        const float L = rl[0] + rl[1] + rl[2] + rl[3];
        float logpsum = 0.f, sim0sum = 0.f;
        #pragma unroll
        for (int b = 0; b < BB; ++b) {
            const float s0 = accSim0[b] * (1.0f / HW);
            sim0sum += s0;
            logpsum += fmaxf(logf(s0), -100.0f);
        }
        out[0] = -(logpsum + L) / ((float)(NEGN + 1) * (float)BB);
        out[1] = sim0sum / (float)BB;
        out[2] = S / (float)NEGN * TEMP / (float)BB;
    }
}

extern "C" void kernel_launch(void* const* d_in, const int* in_sizes, int n_in,
                              void* d_out, int out_size, void* d_ws, size_t ws_size,
                              hipStream_t stream) {
    const float* v1   = (const float*)d_in[0];
    const float* v2   = (const float*)d_in[1];
    const float* img  = (const float*)d_in[2];
    const int*   nidx = (const int*)  d_in[3];

    float* accSim  = (float*)d_ws;            // B*NEG
    float* accSim0 = accSim + BB * NEGN;      // B

    hipMemsetAsync(accSim, 0, (BB * NEGN + BB) * sizeof(float), stream);

    contrastive_fused<<<BB * (HW / PT), 256, 0, stream>>>(
        v1, v2, img, nidx, accSim, accSim0);
    finalize<<<1, 256, 0, stream>>>(accSim, accSim0, (float*)d_out);
}

// Round 2
// 101.935 us; speedup vs baseline: 1.1048x; 1.1048x over previous
//
#include <hip/hip_runtime.h>
#include <math.h>

#define BB 8
#define CC 64
#define HH 32
#define WW 32
#define HW 1024
#define NEGN 256
#define TEMP 2.0f
#define FACTOR 0.8f
#define EPSF 1e-8f
#define PT 8            // p-rows per block

// ---------------------------------------------------------------------------
// Fused kernel: one block per (b, p-tile of 8 rows).
// Phase A: dense GEMM D[pp][q] = sum_c z1[b,c,p0+pp] * z2[b,c,q] for all q.
//          Explicit 4-deep register prefetch ring on the z2 stream (~290 cy
//          of FMAs between load and use -> covers L2 latency). As_s reads are
//          wave-uniform (LDS broadcast, free). Result + per-q norms -> LDS.
// Phase B: round-0 mapping (pp = t>>5, n = lane32+32j): 10 shfls total for
//          the per-p weight reduction. img gathers go straight to L1
//          (12 KB resident) as a batch of 24 independent loads. The per-n
//          simpart buffer is ALIASED into Dt_s (dead after the cos reads,
//          fenced by a barrier) -> no extra LDS.
// LDS: 2 + 32 + 4 + ~0.13 = 38.5 KB -> 4 workgroups/CU; grid 1024 = 4/CU,
//      one residency round. __launch_bounds__(256,4) caps VGPR at 128 (pf
//      ring + acc + gather temps fit in ~100).
// ---------------------------------------------------------------------------
__global__ __launch_bounds__(256, 4) void contrastive_fused(
    const float* __restrict__ z1,    // (B, C, HW)
    const float* __restrict__ z2,    // (B, C, HW)
    const float* __restrict__ img,   // (3, HW)
    const int*   __restrict__ nidx,  // (B, 2, HW, NEG)
    float* __restrict__ accSim,      // (B, NEG)
    float* __restrict__ accSim0)     // (B)
{
    __shared__ float As_s[CC * PT];       // [c][pp]   2 KB
    __shared__ float Dt_s[PT * HW];       // [pp][q]  32 KB (aliased by simpart later)
    __shared__ float normq_s[HW];         //           4 KB
    __shared__ float cen_s[3 * PT];       // [ch][pp]  96 B
    __shared__ float z1sqs[PT];           //           32 B

    const int t  = threadIdx.x;
    const int b  = blockIdx.x >> 7;
    const int p0 = (blockIdx.x & 127) * PT;

    const int lane32 = t & 31;   // n-group lane (phase B)
    const int pp_b   = t >> 5;   // which p this thread handles in phase B
    const int p_b    = p0 + pp_b;

    // ---- stage z1 panel + per-pp img centers into LDS ----
    for (int i = t; i < CC * PT; i += 256) {
        const int c = i >> 3, pp = i & 7;
        As_s[i] = z1[((size_t)(b * CC + c)) * HW + p0 + pp];
    }
    if (t < 3 * PT) cen_s[t] = img[(t >> 3) * HW + p0 + (t & 7)];
    __syncthreads();

    if (t < PT) {
        float s = 0.f;
        #pragma unroll
        for (int c = 0; c < CC; ++c) { const float v = As_s[c * PT + t]; s += v * v; }
        z1sqs[t] = s;
    }

    // ---- phase A: GEMM, thread t owns q = 4t..4t+3 for all 8 p ----
    const float4* __restrict__ z2f4 =
        reinterpret_cast<const float4*>(z2 + (size_t)b * CC * HW);

    float4 acc[PT];
    #pragma unroll
    for (int pp = 0; pp < PT; ++pp) acc[pp] = make_float4(0.f, 0.f, 0.f, 0.f);
    float4 sq = make_float4(0.f, 0.f, 0.f, 0.f);

    // 4-deep prefetch ring (static indices after unroll-by-4)
    float4 pf[4];
    #pragma unroll
    for (int i = 0; i < 4; ++i) pf[i] = z2f4[i * (HW / 4) + t];

#define GEMM_STEP(kk, bv)                                                      \
    {                                                                          \
        sq.x = fmaf((bv).x, (bv).x, sq.x);                                     \
        sq.y = fmaf((bv).y, (bv).y, sq.y);                                     \
        sq.z = fmaf((bv).z, (bv).z, sq.z);                                     \
        sq.w = fmaf((bv).w, (bv).w, sq.w);                                     \
        const float4 a03 = reinterpret_cast<const float4*>(As_s)[(kk) * 2];    \
        const float4 a47 = reinterpret_cast<const float4*>(As_s)[(kk) * 2 + 1];\
        const float av[8] = {a03.x, a03.y, a03.z, a03.w,                       \
                             a47.x, a47.y, a47.z, a47.w};                      \
        _Pragma("unroll")                                                      \
        for (int pp = 0; pp < PT; ++pp) {                                      \
            acc[pp].x = fmaf(av[pp], (bv).x, acc[pp].x);                       \
            acc[pp].y = fmaf(av[pp], (bv).y, acc[pp].y);                       \
            acc[pp].z = fmaf(av[pp], (bv).z, acc[pp].z);                       \
            acc[pp].w = fmaf(av[pp], (bv).w, acc[pp].w);                       \
        }                                                                      \
    }

    #pragma unroll 4
    for (int k = 0; k < CC - 4; ++k) {            // 60 iters = 15 x unroll-4
        const float4 bv = pf[k & 3];
        pf[k & 3] = z2f4[(k + 4) * (HW / 4) + t]; // prefetch k+4
        GEMM_STEP(k, bv);
    }
    #pragma unroll
    for (int k = CC - 4; k < CC; ++k) {           // drain the ring
        const float4 bv = pf[k & 3];
        GEMM_STEP(k, bv);
    }
#undef GEMM_STEP

    float4* Dt4 = reinterpret_cast<float4*>(Dt_s);
    #pragma unroll
    for (int pp = 0; pp < PT; ++pp) Dt4[pp * (HW / 4) + t] = acc[pp];
    reinterpret_cast<float4*>(normq_s)[t] =
        make_float4(sqrtf(sq.x), sqrtf(sq.y), sqrtf(sq.z), sqrtf(sq.w));

    // ---- prefetch nidx (round-0 mapping: n = lane32 + 32*j), issued before
    //      the barrier so HBM latency hides under the drain ----
    int rr[8], cc_[8];
    const size_t nbase = ((size_t)(b * 2) * HW + p_b) * NEGN;
    #pragma unroll
    for (int j = 0; j < 8; ++j) {
        rr[j]  = nidx[nbase + lane32 + 32 * j];
        cc_[j] = nidx[nbase + (size_t)HW * NEGN + lane32 + 32 * j];
    }
    __syncthreads();

    // ---- phase B: gather + weight + sim ----
    const float z1sq = z1sqs[pp_b];
    const float z1n  = sqrtf(z1sq);
    const float cen0 = cen_s[pp_b], cen1 = cen_s[PT + pp_b], cen2 = cen_s[2 * PT + pp_b];
    const float hp = (float)(p_b >> 5), wp = (float)(p_b & 31);

    // batch-issue all independent gathers so latencies overlap
    int   qv[8];
    float g0[8], g1[8], g2[8];
    #pragma unroll
    for (int j = 0; j < 8; ++j) {
        qv[j] = rr[j] * WW + cc_[j];
        g0[j] = img[qv[j]];
        g1[j] = img[HW + qv[j]];
        g2[j] = img[2 * HW + qv[j]];
    }
    float dotv[8], pnn[8];
    #pragma unroll
    for (int j = 0; j < 8; ++j) {
        dotv[j] = Dt_s[pp_b * HW + qv[j]];
        pnn[j]  = normq_s[qv[j]];
    }

    float se = 0.f, sr = 0.f, cosv[8];
    #pragma unroll
    for (int j = 0; j < 8; ++j) {
        const float dh = hp - (float)rr[j], dw = wp - (float)cc_[j];
        se += dh * dh + dw * dw;
        const float d0 = cen0 - g0[j];
        const float d1 = cen1 - g1[j];
        const float d2 = cen2 - g2[j];
        sr += d0 * d0 + d1 * d1 + d2 * d2;
        cosv[j] = dotv[j] / fmaxf(z1n * pnn[j], EPSF);
    }
    // reduce over the 32 lanes sharing this p (xor<=16 stays within the group)
    #pragma unroll
    for (int off = 16; off; off >>= 1) {
        se += __shfl_xor(se, off);
        sr += __shfl_xor(sr, off);
    }
    const float euc_norm = sqrtf((float)((HH - 1) * (HH - 1) + (WW - 1) * (WW - 1)));
    const float weight = sqrtf(se) / euc_norm * FACTOR +
                         sqrtf(sr) / sqrtf(3.0f) * (1.0f - FACTOR);

    float simv[8];
    #pragma unroll
    for (int j = 0; j < 8; ++j)
        simv[j] = fminf(fabsf(cosv[j] * weight), 1.0f);

    __syncthreads();                       // all Dt_s reads done -> safe to alias
    float* simpart = Dt_s;                 // [pp][n], 8 KB reused inside Dt_s
    #pragma unroll
    for (int j = 0; j < 8; ++j)
        simpart[pp_b * NEGN + lane32 + 32 * j] = simv[j];
    __syncthreads();

    // per-n sum over the 8 p's in this block -> one atomic per n
    float s = 0.f;
    #pragma unroll
    for (int pp = 0; pp < PT; ++pp) s += simpart[pp * NEGN + t];
    atomicAdd(accSim + b * NEGN + t, s);

    // sim0 contributions (8 p's) -> one atomic per block
    if (t < PT) {
        const float zz = z1sqs[t];
        const float c0 = zz / fmaxf(zz, EPSF);
        float s0 = fminf(fabsf(c0), 1.0f);
        #pragma unroll
        for (int off = 4; off; off >>= 1) s0 += __shfl_xor(s0, off);
        if (t == 0) atomicAdd(accSim0 + b, s0);
    }
}

// ---------------------------------------------------------------------------
// Finalize: loss is linear in the per-(b,n) sums; one block suffices.
// ---------------------------------------------------------------------------
__global__ __launch_bounds__(256) void finalize(
    const float* __restrict__ accSim,
    const float* __restrict__ accSim0,
    float* __restrict__ out)
{
    const int t = threadIdx.x;
    float ssum = 0.f, lsum = 0.f;
    #pragma unroll
    for (int b = 0; b < BB; ++b) {
        const float s = accSim[b * NEGN + t] * (1.0f / HW) * (1.0f / TEMP);
        ssum += s;
        lsum += fmaxf(log1pf(-s), -100.0f);
    }
    __shared__ float rs[4], rl[4];
    #pragma unroll
    for (int off = 32; off; off >>= 1) {
        ssum += __shfl_down(ssum, off);
        lsum += __shfl_down(lsum, off);
    }
    if ((t & 63) == 0) { rs[t >> 6] = ssum; rl[t >> 6] = lsum; }
    __syncthreads();

    if (t == 0) {
        const float S = rs[0] + rs[1] + rs[2] + rs[3];
        const float L = rl[0] + rl[1] + rl[2] + rl[3];
        float logpsum = 0.f, sim0sum = 0.f;
        #pragma unroll
        for (int b = 0; b < BB; ++b) {
            const float s0 = accSim0[b] * (1.0f / HW);
            sim0sum += s0;
            logpsum += fmaxf(logf(s0), -100.0f);
        }
        out[0] = -(logpsum + L) / ((float)(NEGN + 1) * (float)BB);
        out[1] = sim0sum / (float)BB;
        out[2] = S / (float)NEGN * TEMP / (float)BB;
    }
}

extern "C" void kernel_launch(void* const* d_in, const int* in_sizes, int n_in,
                              void* d_out, int out_size, void* d_ws, size_t ws_size,
                              hipStream_t stream) {
    const float* v1   = (const float*)d_in[0];
    const float* v2   = (const float*)d_in[1];
    const float* img  = (const float*)d_in[2];
    const int*   nidx = (const int*)  d_in[3];

    float* accSim  = (float*)d_ws;            // B*NEG
    float* accSim0 = accSim + BB * NEGN;      // B

    hipMemsetAsync(accSim, 0, (BB * NEGN + BB) * sizeof(float), stream);

    contrastive_fused<<<BB * (HW / PT), 256, 0, stream>>>(
        v1, v2, img, nidx, accSim, accSim0);
    finalize<<<1, 256, 0, stream>>>(accSim, accSim0, (float*)d_out);
}

// Round 3
// 101.066 us; speedup vs baseline: 1.1143x; 1.0086x over previous
//
#include <hip/hip_runtime.h>
#include <math.h>

#define BB 8
#define CC 64
#define HH 32
#define WW 32
#define HW 1024
#define NEGN 256
#define TEMP 2.0f
#define FACTOR 0.8f
#define EPSF 1e-8f
#define PT 8            // p-rows per block

// workspace layout (floats):
//   accSim[BB*NEGN] | accSim0[BB] | z1n[BB*HW] | imgpack[HW*4]
// all section sizes are multiples of 4 floats -> imgpack stays 16B-aligned.

// ---------------------------------------------------------------------------
// prep: replaces the memset dispatch 1:1. Zeroes accSim, packs img into an
// interleaved float4 table (1 gather instead of 3 in fused phase B), computes
// z1n[b,p] (consumed race-free by fused's cos epilogue) and the exact
// accSim0[b] = sum_p min(|z1sq/max(z1sq,eps)|,1).
// ---------------------------------------------------------------------------
__global__ __launch_bounds__(256) void prep(
    const float* __restrict__ z1,     // (B, C, HW)
    const float* __restrict__ img,    // (3, HW)
    float* __restrict__ accSim,       // (B, NEG)
    float* __restrict__ accSim0,      // (B)
    float* __restrict__ z1n_ws,       // (B, HW)
    float4* __restrict__ imgpack)     // (HW)
{
    const int b = blockIdx.x;         // BB blocks
    const int t = threadIdx.x;

    accSim[b * NEGN + t] = 0.f;

    if (t < HW / BB) {                // 128 q's per block
        const int q = b * (HW / BB) + t;
        imgpack[q] = make_float4(img[q], img[HW + q], img[2 * HW + q], 0.f);
    }

    // z1 norms: thread t owns p = 4t..4t+3 (coalesced float4 over c-loop)
    const float4* __restrict__ z1b =
        reinterpret_cast<const float4*>(z1 + (size_t)b * CC * HW);
    float4 s = make_float4(0.f, 0.f, 0.f, 0.f);
    #pragma unroll 8
    for (int c = 0; c < CC; ++c) {
        const float4 v = z1b[c * (HW / 4) + t];
        s.x = fmaf(v.x, v.x, s.x);
        s.y = fmaf(v.y, v.y, s.y);
        s.z = fmaf(v.z, v.z, s.z);
        s.w = fmaf(v.w, v.w, s.w);
    }
    reinterpret_cast<float4*>(z1n_ws + (size_t)b * HW)[t] =
        make_float4(sqrtf(s.x), sqrtf(s.y), sqrtf(s.z), sqrtf(s.w));

    float s0 = fminf(fabsf(s.x / fmaxf(s.x, EPSF)), 1.0f)
             + fminf(fabsf(s.y / fmaxf(s.y, EPSF)), 1.0f)
             + fminf(fabsf(s.z / fmaxf(s.z, EPSF)), 1.0f)
             + fminf(fabsf(s.w / fmaxf(s.w, EPSF)), 1.0f);
    #pragma unroll
    for (int off = 32; off; off >>= 1) s0 += __shfl_down(s0, off);
    __shared__ float red[4];
    if ((t & 63) == 0) red[t >> 6] = s0;
    __syncthreads();
    if (t == 0) accSim0[b] = red[0] + red[1] + red[2] + red[3];
}

// ---------------------------------------------------------------------------
// Fused kernel: one block per (b, p-tile of 8 rows).
// Phase A: dense GEMM. A-panel read via WAVE-UNIFORM global loads (addresses
//          depend only on blockIdx -> compiler scalarizes to s_load through
//          the K$, shared by all 4 waves) -> the k-loop has ZERO DS traffic:
//          1 VMEM float4 (4-deep prefetch ring) + 36 FMA per k.
//          Epilogue converts dot -> cos in place (this thread owns the sq of
//          its 4 q's; z1n from prep via uniform load; eps clamp exactly
//          max(z1n*pnn, EPS) as in the reference) and stores cos in Dt_s.
// Phase B: per (p,n): ONE float4 imgpack gather (L1, 16 KB resident) + ONE
//          LDS cos gather. nidx loaded as int2 (n = 2*lane + 64*j). Weight
//          via 10-shfl half-wave butterfly. simpart aliased into Dt_s.
// LDS: 32 KB -> 4 workgroups/CU, grid 1024 = one residency round.
// ---------------------------------------------------------------------------
__global__ __launch_bounds__(256, 4) void contrastive_fused(
    const float* __restrict__ z1,     // (B, C, HW)
    const float* __restrict__ z2,     // (B, C, HW)
    const int*   __restrict__ nidx,   // (B, 2, HW, NEG)
    const float* __restrict__ z1n_ws, // (B, HW)
    const float4* __restrict__ imgpack, // (HW)
    float* __restrict__ accSim)       // (B, NEG)
{
    __shared__ float Dt_s[PT * HW];   // 32 KB: cos matrix, later simpart alias

    const int t  = threadIdx.x;
    const int b  = blockIdx.x >> 7;
    const int p0 = (blockIdx.x & 127) * PT;

    const int lane32 = t & 31;        // n-group lane (phase B)
    const int pp_b   = t >> 5;        // which p this thread handles in phase B
    const int p_b    = p0 + pp_b;

    // ---- phase A: GEMM, thread t owns q = 4t..4t+3 for all 8 p ----
    const float4* __restrict__ z2f4 =
        reinterpret_cast<const float4*>(z2 + (size_t)b * CC * HW);
    const float* __restrict__ z1row = z1 + (size_t)(b * CC) * HW + p0; // uniform

    float4 acc[PT];
    #pragma unroll
    for (int pp = 0; pp < PT; ++pp) acc[pp] = make_float4(0.f, 0.f, 0.f, 0.f);
    float4 sq = make_float4(0.f, 0.f, 0.f, 0.f);

    float4 pf[4];
    #pragma unroll
    for (int i = 0; i < 4; ++i) pf[i] = z2f4[i * (HW / 4) + t];

#define GEMM_STEP(kk, bv)                                                      \
    {                                                                          \
        sq.x = fmaf((bv).x, (bv).x, sq.x);                                     \
        sq.y = fmaf((bv).y, (bv).y, sq.y);                                     \
        sq.z = fmaf((bv).z, (bv).z, sq.z);                                     \
        sq.w = fmaf((bv).w, (bv).w, sq.w);                                     \
        _Pragma("unroll")                                                      \
        for (int pp = 0; pp < PT; ++pp) {                                      \
            const float a = z1row[(kk) * HW + pp]; /* uniform -> s_load */     \
            acc[pp].x = fmaf(a, (bv).x, acc[pp].x);                            \
            acc[pp].y = fmaf(a, (bv).y, acc[pp].y);                            \
            acc[pp].z = fmaf(a, (bv).z, acc[pp].z);                            \
            acc[pp].w = fmaf(a, (bv).w, acc[pp].w);                            \
        }                                                                      \
    }

    #pragma unroll 4
    for (int k = 0; k < CC - 4; ++k) {            // 60 iters
        const float4 bv = pf[k & 3];
        pf[k & 3] = z2f4[(k + 4) * (HW / 4) + t]; // prefetch k+4
        GEMM_STEP(k, bv);
    }
    #pragma unroll
    for (int k = CC - 4; k < CC; ++k) {           // drain
        const float4 bv = pf[k & 3];
        GEMM_STEP(k, bv);
    }
#undef GEMM_STEP

    // ---- epilogue: dot -> cos, store in Dt_s ----
    const float* __restrict__ z1nrow = z1n_ws + (size_t)b * HW + p0; // uniform
    float z1nv[PT];
    #pragma unroll
    for (int pp = 0; pp < PT; ++pp) z1nv[pp] = z1nrow[pp];
    const float4 pnn = make_float4(sqrtf(sq.x), sqrtf(sq.y),
                                   sqrtf(sq.z), sqrtf(sq.w));
    float4* Dt4 = reinterpret_cast<float4*>(Dt_s);
    #pragma unroll
    for (int pp = 0; pp < PT; ++pp) {
        float4 cv;
        cv.x = acc[pp].x / fmaxf(z1nv[pp] * pnn.x, EPSF);
        cv.y = acc[pp].y / fmaxf(z1nv[pp] * pnn.y, EPSF);
        cv.z = acc[pp].z / fmaxf(z1nv[pp] * pnn.z, EPSF);
        cv.w = acc[pp].w / fmaxf(z1nv[pp] * pnn.w, EPSF);
        Dt4[pp * (HW / 4) + t] = cv;
    }

    // ---- nidx prefetch (int2; n = 2*lane32 + 64*j), before the barrier ----
    const size_t nbase = ((size_t)(b * 2) * HW + p_b) * NEGN;
    const int2* __restrict__ nr = reinterpret_cast<const int2*>(nidx + nbase);
    const int2* __restrict__ nc =
        reinterpret_cast<const int2*>(nidx + nbase + (size_t)HW * NEGN);
    int2 rrv[4], ccv[4];
    #pragma unroll
    for (int j = 0; j < 4; ++j) {
        rrv[j] = nr[lane32 + 32 * j];
        ccv[j] = nc[lane32 + 32 * j];
    }
    __syncthreads();

    // ---- phase B ----
    const float4 cen = imgpack[p_b];
    const float hp = (float)(p_b >> 5), wp = (float)(p_b & 31);

    int q[8];
    #pragma unroll
    for (int j = 0; j < 4; ++j) {
        q[2 * j]     = rrv[j].x * WW + ccv[j].x;
        q[2 * j + 1] = rrv[j].y * WW + ccv[j].y;
    }
    // batch-issue all independent gathers so latencies overlap
    float4 g[8];
    #pragma unroll
    for (int e = 0; e < 8; ++e) g[e] = imgpack[q[e]];
    float cg[8];
    #pragma unroll
    for (int e = 0; e < 8; ++e) cg[e] = Dt_s[pp_b * HW + q[e]];

    float se = 0.f, sr = 0.f;
    #pragma unroll
    for (int j = 0; j < 4; ++j) {
        {
            const float dh = hp - (float)rrv[j].x, dw = wp - (float)ccv[j].x;
            se += dh * dh + dw * dw;
            const float d0 = cen.x - g[2 * j].x;
            const float d1 = cen.y - g[2 * j].y;
            const float d2 = cen.z - g[2 * j].z;
            sr += d0 * d0 + d1 * d1 + d2 * d2;
        }
        {
            const float dh = hp - (float)rrv[j].y, dw = wp - (float)ccv[j].y;
            se += dh * dh + dw * dw;
            const float d0 = cen.x - g[2 * j + 1].x;
            const float d1 = cen.y - g[2 * j + 1].y;
            const float d2 = cen.z - g[2 * j + 1].z;
            sr += d0 * d0 + d1 * d1 + d2 * d2;
        }
    }
    // reduce over the 32 lanes sharing this p (xor<=16 stays in the group)
    #pragma unroll
    for (int off = 16; off; off >>= 1) {
        se += __shfl_xor(se, off);
        sr += __shfl_xor(sr, off);
    }
    const float euc_norm = sqrtf((float)((HH - 1) * (HH - 1) + (WW - 1) * (WW - 1)));
    const float weight = sqrtf(se) / euc_norm * FACTOR +
                         sqrtf(sr) / sqrtf(3.0f) * (1.0f - FACTOR);

    float2 sv[4];
    #pragma unroll
    for (int j = 0; j < 4; ++j) {
        sv[j].x = fminf(fabsf(cg[2 * j]     * weight), 1.0f);
        sv[j].y = fminf(fabsf(cg[2 * j + 1] * weight), 1.0f);
    }

    __syncthreads();                       // all Dt_s reads done -> alias safe
    float2* simpart2 = reinterpret_cast<float2*>(Dt_s);  // [pp][n/2]
    #pragma unroll
    for (int j = 0; j < 4; ++j)
        simpart2[pp_b * (NEGN / 2) + lane32 + 32 * j] = sv[j];
    __syncthreads();

    // per-n sum over the 8 p's in this block -> one atomic per n
    float s = 0.f;
    #pragma unroll
    for (int pp = 0; pp < PT; ++pp) s += Dt_s[pp * NEGN + t];
    atomicAdd(accSim + b * NEGN + t, s);
}

// ---------------------------------------------------------------------------
// Finalize: loss is linear in the per-(b,n) sums; one block suffices.
// ---------------------------------------------------------------------------
__global__ __launch_bounds__(256) void finalize(
    const float* __restrict__ accSim,
    const float* __restrict__ accSim0,
    float* __restrict__ out)
{
    const int t = threadIdx.x;
    float ssum = 0.f, lsum = 0.f;
    #pragma unroll
    for (int b = 0; b < BB; ++b) {
        const float s = accSim[b * NEGN + t] * (1.0f / HW) * (1.0f / TEMP);
        ssum += s;
        lsum += fmaxf(log1pf(-s), -100.0f);
    }
    __shared__ float rs[4], rl[4];
    #pragma unroll
    for (int off = 32; off; off >>= 1) {
        ssum += __shfl_down(ssum, off);
        lsum += __shfl_down(lsum, off);
    }
    if ((t & 63) == 0) { rs[t >> 6] = ssum; rl[t >> 6] = lsum; }
    __syncthreads();

    if (t == 0) {
        const float S = rs[0] + rs[1] + rs[2] + rs[3];
        const float L = rl[0] + rl[1] + rl[2] + rl[3];
        float logpsum = 0.f, sim0sum = 0.f;
        #pragma unroll
        for (int b = 0; b < BB; ++b) {
            const float s0 = accSim0[b] * (1.0f / HW);
            sim0sum += s0;
            logpsum += fmaxf(logf(s0), -100.0f);
        }
        out[0] = -(logpsum + L) / ((float)(NEGN + 1) * (float)BB);
        out[1] = sim0sum / (float)BB;
        out[2] = S / (float)NEGN * TEMP / (float)BB;
    }
}

extern "C" void kernel_launch(void* const* d_in, const int* in_sizes, int n_in,
                              void* d_out, int out_size, void* d_ws, size_t ws_size,
                              hipStream_t stream) {
    const float* v1   = (const float*)d_in[0];
    const float* v2   = (const float*)d_in[1];
    const float* img  = (const float*)d_in[2];
    const int*   nidx = (const int*)  d_in[3];

    float* ws      = (float*)d_ws;
    float* accSim  = ws;                          // BB*NEGN
    float* accSim0 = accSim + BB * NEGN;          // BB
    float* z1n_ws  = accSim0 + BB;                // BB*HW
    float4* imgpack = (float4*)(z1n_ws + BB * HW); // HW float4 (16B-aligned)

    prep<<<BB, 256, 0, stream>>>(v1, img, accSim, accSim0, z1n_ws, imgpack);
    contrastive_fused<<<BB * (HW / PT), 256, 0, stream>>>(
        v1, v2, nidx, z1n_ws, imgpack, accSim);
    finalize<<<1, 256, 0, stream>>>(accSim, accSim0, (float*)d_out);
}